// Round 2
// baseline (65.242 us; speedup 1.0000x reference)
//
#include <hip/hip_runtime.h>
#include <math.h>

#define HH 256
#define WW 256
#define CC 3
#define HW (HH*WW)

// Output tile: 64 wide x 8 tall per block; 256 threads; 2 horizontal outputs/thread.
// Input tile in LDS: 72 cols x 16 rows x 3 channels.
#define TW 64
#define TH 8
#define IW 72
#define IH 16
#define LDS_CH (IW*IH)      // 1152
#define LDS_TOT (LDS_CH*CC) // 3456

__device__ __forceinline__ int reflect(int v, int n) {
    v = (v < 0) ? -v : v;
    v = (v > n - 1) ? (2 * (n - 1) - v) : v;
    return v;
}

// dense index for the 16 distinct r^2 values in a 9x9 window
__device__ __forceinline__ constexpr int r2idx(int r2) {
    switch (r2) {
        case 0:  return 0;  case 1:  return 1;  case 2:  return 2;  case 4:  return 3;
        case 5:  return 4;  case 8:  return 5;  case 9:  return 6;  case 10: return 7;
        case 13: return 8;  case 16: return 9;  case 17: return 10; case 18: return 11;
        case 20: return 12; case 25: return 13; case 26: return 14; default: return 15; // 32
    }
}

__global__ __launch_bounds__(256) void adaptive_log_kernel(
    const float* __restrict__ x, const float* __restrict__ foa,
    float* __restrict__ out)
{
    __shared__ float lds[LDS_TOT];
    const int tid = threadIdx.x;
    const int bx = blockIdx.x & 3;    // 0..3   x-tile
    const int by = blockIdx.x >> 2;   // 0..31  y-tile
    const int b  = blockIdx.y;

    const int gx0 = bx * TW;
    const int gy0 = by * TH;

    // ---- stage input tile into LDS (reflect padding resolved here) ----
    const float* xb = x + (size_t)b * (CC * HW);
    for (int i = tid; i < LDS_TOT; i += 256) {
        int c   = i / LDS_CH;
        int rem = i - c * LDS_CH;
        int r   = rem / IW;
        int col = rem - r * IW;
        int gr = reflect(gy0 + r - 4, HH);
        int gc = reflect(gx0 + col - 4, WW);
        lds[i] = xb[c * HW + gr * WW + gc];
    }
    __syncthreads();

    const int tx = tid & 31;   // 0..31 -> output cols gx0 + 2*tx, +1
    const int ty = tid >> 5;   // 0..7  -> output row  gy0 + ty

    const int px0 = gx0 + tx * 2;
    const int py  = gy0 + ty;

    // ---- per-output weight tables: 1 exp + 15 muls each ----
    const float fx = foa[2 * b + 0];
    const float fy = foa[2 * b + 1];

    float w0[16], w1[16];
    #pragma unroll
    for (int o = 0; o < 2; ++o) {
        float* w = o ? w1 : w0;
        const float ddx = (float)(px0 + o) - fx;
        const float ddy = (float)py - fy;
        const float dist = sqrtf(ddx * ddx + ddy * ddy);
        const float dn = dist * (1.0f / 362.03867196751236f); // 1/sqrt(2*256^2)
        const float sigma = 0.5f + 9.5f * dn;
        const float s2 = sigma * sigma;
        const float inv2s2 = 0.5f / s2;
        const float common = (-1.0f / (float)M_PI) / (s2 * s2) * sqrtf(sigma) * dist;
        const float q  = __expf(-inv2s2);   // q^(r^2) gives exp(-r^2/(2s^2))
        const float q2 = q * q;
        const float q4 = q2 * q2;
        const float q8 = q4 * q4;
        const float q16 = q8 * q8;
        float e[16];
        e[0] = 1.0f;      e[1] = q;          e[2] = q2;         e[3] = q4;
        e[4] = q4 * q;    e[5] = q8;         e[6] = q8 * q;     e[7] = q8 * q2;
        e[8] = q8 * q4 * q; /*13*/           e[9] = q16;        e[10] = q16 * q;
        e[11] = q16 * q2; e[12] = q16 * q4;  e[13] = q16 * q8 * q;  /*25*/
        e[14] = q16 * q8 * q2; /*26*/        e[15] = q16 * q16; /*32*/
        const float r2v[16] = {0,1,2,4,5,8,9,10,13,16,17,18,20,25,26,32};
        #pragma unroll
        for (int k = 0; k < 16; ++k)
            w[k] = common * (1.0f - r2v[k] * inv2s2) * e[k];
    }

    // ---- 9x9 conv over 3 channels from LDS; 5x float2 reads per row ----
    float acc0[CC] = {0.f, 0.f, 0.f};  // output at px0
    float acc1[CC] = {0.f, 0.f, 0.f};  // output at px0+1
    #pragma unroll
    for (int c = 0; c < CC; ++c) {
        #pragma unroll
        for (int i = 0; i < 9; ++i) {
            // lds row (ty+i), cols tx*2 .. tx*2+9  (all even-aligned for float2)
            const float2* row = (const float2*)&lds[c * LDS_CH + (ty + i) * IW + tx * 2];
            const float2 f01 = row[0];
            const float2 f23 = row[1];
            const float2 f45 = row[2];
            const float2 f67 = row[3];
            const float2 f89 = row[4];
            const float f[10] = {f01.x, f01.y, f23.x, f23.y, f45.x,
                                 f45.y, f67.x, f67.y, f89.x, f89.y};
            const int dy2 = (i - 4) * (i - 4);
            float s0 = 0.f, s1 = 0.f;
            #pragma unroll
            for (int m = 0; m < 9; ++m) {
                const int dx2 = (m - 4) * (m - 4);
                s0 += w0[r2idx(dy2 + dx2)] * f[m];
                s1 += w1[r2idx(dy2 + dx2)] * f[m + 1];
            }
            acc0[c] += s0;
            acc1[c] += s1;
        }
    }

    // ---- coalesced float2 stores ----
    float* ob = out + (size_t)b * (CC * HW) + py * WW + px0;
    #pragma unroll
    for (int c = 0; c < CC; ++c) {
        *(float2*)&ob[c * HW] = make_float2(acc0[c], acc1[c]);
    }
}

extern "C" void kernel_launch(void* const* d_in, const int* in_sizes, int n_in,
                              void* d_out, int out_size, void* d_ws, size_t ws_size,
                              hipStream_t stream) {
    const float* x   = (const float*)d_in[0];   // [4,3,256,256] f32
    const float* foa = (const float*)d_in[1];   // [4,2] f32
    float* out = (float*)d_out;                 // [4,3,256,256] f32

    dim3 grid(4 * 32, 4);   // (x-tiles * y-tiles, batch) = 512 blocks
    dim3 block(256);
    adaptive_log_kernel<<<grid, block, 0, stream>>>(x, foa, out);
}